// Round 13
// baseline (88.646 us; speedup 1.0000x reference)
//
#include <hip/hip_runtime.h>
#include <hip/hip_bf16.h>
#include <stdint.h>

#define BB 8
#define NN 2048
#define MM 2048
#define CC 256

typedef __attribute__((ext_vector_type(8))) short short8;
typedef __attribute__((ext_vector_type(4))) float f32x4;

__device__ __forceinline__ void gl_lds16(const void* g, void* l) {
    __builtin_amdgcn_global_load_lds(
        (const __attribute__((address_space(1))) void*)g,
        (__attribute__((address_space(3))) void*)l, 16, 0, 0);
}

__device__ __forceinline__ unsigned short f2bf(float f) {
    __hip_bfloat16 h = __float2bfloat16(f);
    return *reinterpret_cast<unsigned short*>(&h);
}

// ---------------- normalize + cast + layout pre-pass (+acc zeroing) ----------------
// One wave per row of C=256 floats.
// A layout (bytes): row*512 + c*64 + kbL*16 + (lane&1)*8, kbL = kb ^ ((row>>1)&3)
//   (row-major full-K per row; fused stages it linearly via gl_lds -> swizzled LDS)
// B layout (bytes): b<<20 + (r>>6)<<15 + c*4096 + ((r>>4)&3)<<10 + kbL*256
//                   + (r&15)*16 + (lane&1)*8
//   -> per (batch, 64-col m-tile): 32 KB contiguous; each MFMA B-fragment is a
//      coalesced 1 KiB block read straight to registers (same inner layout as R5).
__global__ __launch_bounds__(256) void norm_cast_kernel(
    const float* __restrict__ x1, const float* __restrict__ x2,
    char* __restrict__ outA, char* __restrict__ outB,
    float* __restrict__ lsum, unsigned int* __restrict__ vcnt,
    unsigned int* __restrict__ flags, unsigned int* __restrict__ done) {
    if (blockIdx.x == 0 && threadIdx.x < 8) {
        int t = threadIdx.x;
        lsum[t] = 0.0f; vcnt[t] = 0u; flags[t] = 0u; flags[BB + t] = 0u;
        if (t == 0) *done = 0u;
    }
    int gwave = (blockIdx.x * blockDim.x + threadIdx.x) >> 6;
    int lane  = threadIdx.x & 63;
    bool isA = gwave < BB * NN;
    const float* src = isA ? x1 : x2;
    int row = isA ? gwave : gwave - BB * NN;
    float4 v = reinterpret_cast<const float4*>(src + (size_t)row * CC)[lane];
    float ss = v.x * v.x + v.y * v.y + v.z * v.z + v.w * v.w;
#pragma unroll
    for (int off = 32; off; off >>= 1) ss += __shfl_xor(ss, off);
    float inv = 1.0f / fmaxf(sqrtf(ss), 1e-8f);
    ushort4 h;
    h.x = f2bf(v.x * inv); h.y = f2bf(v.y * inv);
    h.z = f2bf(v.z * inv); h.w = f2bf(v.w * inv);
    int c   = lane >> 3;              // k-chunk 0..7
    int kb  = (lane >> 1) & 3;        // 16B k-unit
    int kbL = kb ^ ((row >> 1) & 3);  // swizzle (bits 1-2 of row == bits of col&15)
    char* p;
    if (isA) {
        p = outA + (size_t)row * 512 + c * 64 + kbL * 16 + (lane & 1) * 8;
    } else {
        int b = row >> 11, r = row & 2047;
        p = outB + ((size_t)b << 20) + ((size_t)(r >> 6) << 15) + c * 4096
                 + (((r >> 4) & 3) << 10) + kbL * 256 + (r & 15) * 16 + (lane & 1) * 8;
    }
    *reinterpret_cast<ushort4*>(p) = h;
}

// ---------------- fused MFMA cos-sim + BCE reduce + finalize ----------------
// 1024 blocks x 256 thr (4 waves, 2x2), launch_bounds(256,4): 128-VGPR cap,
// LDS 48.5 KB -> 3 blocks/CU (12 waves/CU). b = blockIdx&7 (XCD == batch).
// Per block: 64-row A-panel full-K in LDS (staged once); 8 m-tiles of 64 cols.
// Per tile: 16 inline-asm global_load_dwordx4 B loads (bulk-issued, compiler
// cannot serialize or insert waits) -> 4 z-DMA to LDS (younger in vm queue)
// -> vmcnt(4): B done, z still in flight under the MFMA chain -> 32 MFMA ->
// vmcnt(0)+barrier -> epilogue reads z from LDS. Counted vmcnt is exact since
// all in-loop VMEM ops are ours (asm + gl_lds).
__global__ __launch_bounds__(256, 4) void fused_mfma_kernel(
    const int*  __restrict__ z,
    const char* __restrict__ nA, const char* __restrict__ nB,
    const float* __restrict__ tptr, const float* __restrict__ bptr,
    float* __restrict__ lsum, unsigned int* __restrict__ vcnt,
    unsigned int* __restrict__ flags, unsigned int* __restrict__ done,
    float* __restrict__ out) {

    __shared__ __align__(16) char ldsA[32768];   // 8 chunks x 64 rows x 64 B
    __shared__ __align__(16) char ldsZ[16384];   // 64 rows x 256 B (one 64x64 z tile)
    __shared__ float        s_sum[4];
    __shared__ unsigned int s_cnt[4];
    __shared__ unsigned int s_flag[2];

    const int flat = blockIdx.x;
    const int b    = flat & 7;            // XCD id == batch
    const int rest = flat >> 3;           // 0..127
    const int ny   = rest & 31;           // 64-row n-panel
    const int n0   = ny * 64;
    const int ms   = rest >> 5;           // 0..3 (512-col m-span)
    const int tid  = threadIdx.x, lane = tid & 63, wid = tid >> 6;
    const int wr = wid >> 1, wc = wid & 1, l15 = lane & 15;
    const int q4  = (lane >> 4) << 2;
    const int kbL = (lane >> 4) ^ ((l15 >> 1) & 3);

    // ---- A staging: wave wid stages chunks wid*2, wid*2+1 (4 KB each) ----
    {
        const char* srcb = nA + ((size_t)b * NN + n0) * 512;
#pragma unroll
        for (int cc = 0; cc < 2; cc++) {
            int c = wid * 2 + cc;
            const char* src = srcb + (size_t)(lane >> 2) * 512 + c * 64 + (lane & 3) * 16;
            char* dst = ldsA + c * 4096;
#pragma unroll
            for (int g = 0; g < 4; g++)
                gl_lds16(src + (size_t)g * 16 * 512, dst + g * 1024);
        }
    }

    // B voffsets (tile-invariant): chunk c at c*4096, this wave's frag pair at
    // wc*2048 (+1024 imm for second frag), inner kbL*256 + l15*16.
    int voffB[8];
#pragma unroll
    for (int c = 0; c < 8; c++)
        voffB[c] = c * 4096 + wc * 2048 + kbL * 256 + l15 * 16;

    const char* zrow0 = (const char*)(z + (((size_t)b * NN + n0) * MM) + ms * 512);

    const float tv = *tptr;
    const float bs = *bptr;
    const float LOG2E = 1.4426950408889634f;
    const float LN2   = 0.6931471805599453f;

    __syncthreads();   // A resident; vmcnt drained -> in-loop counts exact

    float lsu = 0.0f;
    int   lcnt = 0;
    bool  anyp = false, anyn = false;

#pragma unroll
    for (int mt = 0; mt < 8; mt++) {
        const char* sB = nB + ((size_t)b << 20) + ((size_t)(ms * 8 + mt) << 15);

        // ---- bulk B issue: 16 asm loads, back-to-back in the vm queue ----
        short8 bfr[8][2];
#pragma unroll
        for (int c = 0; c < 8; c++) {
            asm volatile("global_load_dwordx4 %0, %1, %2"
                         : "=v"(bfr[c][0]) : "v"(voffB[c]), "s"(sB) : "memory");
            asm volatile("global_load_dwordx4 %0, %1, %2 offset:1024"
                         : "=v"(bfr[c][1]) : "v"(voffB[c]), "s"(sB) : "memory");
        }

        // ---- z DMA: 4 per wave, younger than B in the queue ----
        {
            const char* zsrc = zrow0 + (size_t)mt * 256;
#pragma unroll
            for (int d = 0; d < 4; d++) {
                int i = wid * 4 + d;
                gl_lds16(zsrc + (size_t)(i * 4 + (lane >> 4)) * (MM * 4) + l15 * 16,
                         ldsZ + i * 1024);
            }
        }

        asm volatile("s_waitcnt vmcnt(4)" ::: "memory");   // B done; z in flight
        __builtin_amdgcn_sched_barrier(0);

        // ---- MFMA over full K (wave-tile 32x32) ----
        f32x4 acc[2][2] = {};
#pragma unroll
        for (int c = 0; c < 8; c++) {
            short8 af0 = *reinterpret_cast<const short8*>(
                ldsA + c * 4096 + (wr * 32 + l15) * 64 + kbL * 16);
            short8 af1 = *reinterpret_cast<const short8*>(
                ldsA + c * 4096 + (wr * 32 + 16 + l15) * 64 + kbL * 16);
            acc[0][0] = __builtin_amdgcn_mfma_f32_16x16x32_bf16(af0, bfr[c][0], acc[0][0], 0, 0, 0);
            acc[0][1] = __builtin_amdgcn_mfma_f32_16x16x32_bf16(af0, bfr[c][1], acc[0][1], 0, 0, 0);
            acc[1][0] = __builtin_amdgcn_mfma_f32_16x16x32_bf16(af1, bfr[c][0], acc[1][0], 0, 0, 0);
            acc[1][1] = __builtin_amdgcn_mfma_f32_16x16x32_bf16(af1, bfr[c][1], acc[1][1], 0, 0, 0);
        }

        asm volatile("s_waitcnt vmcnt(0)" ::: "memory");   // this wave's z landed
        __syncthreads();                                   // all waves' z landed
        __builtin_amdgcn_sched_barrier(0);

        // ---- epilogue: z from LDS + exp2-domain log-sigmoid ----
#pragma unroll
        for (int m = 0; m < 2; m++)
#pragma unroll
            for (int rr = 0; rr < 4; rr++)
#pragma unroll
                for (int n = 0; n < 2; n++) {
                    int zij = *reinterpret_cast<const int*>(
                        ldsZ + (wr * 32 + m * 16 + q4 + rr) * 256
                             + (wc * 32 + n * 16 + l15) * 4);
                    float cs = acc[m][n][rr];
                    float pp = fmaf(tv, cs, -bs);
                    float y  = (zij < 0) ? -pp : pp;
                    float e  = __builtin_amdgcn_exp2f(-fabsf(y) * LOG2E);
                    float lg = __builtin_amdgcn_logf(1.0f + e);
                    float ls = fminf(y, 0.0f) - LN2 * lg;
                    if (zij != 0) { lsu += ls; lcnt++; }
                    anyp |= (zij > 0);
                    anyn |= (zij < 0);
                }

        __syncthreads();   // epilogue reads done before next tile's z DMA overwrites
    }

    // ---------------- block reduction (4 waves) ----------------
#pragma unroll
    for (int off = 32; off; off >>= 1) {
        lsu  += __shfl_down(lsu, off);
        lcnt += __shfl_down(lcnt, off);
    }
    unsigned long long mp = __ballot(anyp);
    unsigned long long mn = __ballot(anyn);

    __syncthreads();
    if (tid < 2) s_flag[tid] = 0u;
    __syncthreads();
    if (lane == 0) {
        s_sum[wid] = lsu;
        s_cnt[wid] = (unsigned int)lcnt;
        if (mp) atomicOr(&s_flag[0], 1u);
        if (mn) atomicOr(&s_flag[1], 1u);
    }
    __syncthreads();
    if (tid == 0) {
        float ts = s_sum[0] + s_sum[1] + s_sum[2] + s_sum[3];
        unsigned int tc = s_cnt[0] + s_cnt[1] + s_cnt[2] + s_cnt[3];
        atomicAdd(&lsum[b], ts);
        atomicAdd(&vcnt[b], tc);
        if (s_flag[0]) atomicOr(&flags[b], 1u);
        if (s_flag[1]) atomicOr(&flags[BB + b], 1u);
        __threadfence();
        unsigned int old = atomicAdd(done, 1u);
        if (old == gridDim.x - 1) {
            __threadfence();
            double s = 0.0, c = 0.0;
#pragma unroll
            for (int bb = 0; bb < BB; bb++) {
                unsigned int fp = atomicOr(&flags[bb], 0u);
                unsigned int fn = atomicOr(&flags[BB + bb], 0u);
                float        sv = atomicAdd(&lsum[bb], 0.0f);
                unsigned int cv = atomicAdd(&vcnt[bb], 0u);
                if (fp && fn) { s += (double)sv; c += (double)cv; }
            }
            out[0] = (float)(-s / c);
        }
    }
}

extern "C" void kernel_launch(void* const* d_in, const int* in_sizes, int n_in,
                              void* d_out, int out_size, void* d_ws, size_t ws_size,
                              hipStream_t stream) {
    const int*   z   = (const int*)  d_in[0];
    const float* x1  = (const float*)d_in[1];
    const float* x2  = (const float*)d_in[2];
    const float* tp  = (const float*)d_in[3];
    const float* bp  = (const float*)d_in[4];
    float* out = (float*)d_out;

    char* ws = (char*)d_ws;
    char*  normA = ws;                                  // 8 MiB
    char*  normB = ws + (size_t)BB * NN * 512;          // 8 MiB
    char*  accb  = ws + (size_t)BB * (NN + MM) * 512;
    float*        lsum  = (float*)accb;
    unsigned int* vcnt  = (unsigned int*)(accb + 64);
    unsigned int* flags = (unsigned int*)(accb + 128);
    unsigned int* done  = (unsigned int*)(accb + 256);

    hipLaunchKernelGGL(norm_cast_kernel, dim3(BB * (NN + MM) / 4), dim3(256), 0, stream,
                       x1, x2, normA, normB, lsum, vcnt, flags, done);

    hipLaunchKernelGGL(fused_mfma_kernel, dim3(1024), dim3(256), 0, stream,
                       z, normA, normB, tp, bp, lsum, vcnt, flags, done, out);
}